// Round 2
// baseline (372.769 us; speedup 1.0000x reference)
//
#include <hip/hip_runtime.h>
#include <math.h>

// Problem constants (from reference): B=8, S=8192, D=1024, keep_ratio=0.5
#define BB 8
#define SS 8192
#define DD 1024

// ---------------------------------------------------------------------------
// Kernel 1: scores[token] = dot(hidden[token,:], w) + b  (or -inf if inactive)
// One wave (64 lanes) per token; each lane reads 4x float4 (16 floats).
// Pure HBM streaming: 256 MB of hidden_states. Scores staged in d_out (fp32),
// overwritten by kernel 2 with the int32 keep mask.
// ---------------------------------------------------------------------------
__global__ __launch_bounds__(256) void score_kernel(
    const float* __restrict__ hs, const int* __restrict__ mask,
    const float* __restrict__ w, const float* __restrict__ bias,
    float* __restrict__ scores)
{
    const int wid = threadIdx.x >> 6;
    const int lane = threadIdx.x & 63;
    const int token = blockIdx.x * 4 + wid;   // 0..65535

    const float4* hp = (const float4*)(hs + (size_t)token * DD);
    const float4* wp = (const float4*)w;

    float sum = 0.f;
#pragma unroll
    for (int j = 0; j < 4; ++j) {
        float4 h = hp[lane + j * 64];
        float4 ww = wp[lane + j * 64];
        sum += h.x * ww.x + h.y * ww.y + h.z * ww.z + h.w * ww.w;
    }
#pragma unroll
    for (int off = 32; off > 0; off >>= 1)
        sum += __shfl_down(sum, off, 64);

    if (lane == 0) {
        bool act = mask[token] != 0;
        scores[token] = act ? (sum + bias[0]) : -INFINITY;
    }
}

// ---------------------------------------------------------------------------
// Kernel 2: per-row top-k via 4-round radix select on order-preserving uint
// keys, with stable (lowest-index-first) tie handling to match jnp.argsort.
// One block (1024 threads) per row; 8 blocks total. Reads fp32 scores from
// `buf`, overwrites the same buffer with int32 0/1 (safe: row fully staged in
// LDS + __syncthreads before first write).
// ---------------------------------------------------------------------------
__global__ __launch_bounds__(1024) void select_kernel(
    const int* __restrict__ mask, float* __restrict__ buf)
{
    __shared__ unsigned int keys[SS];          // 32 KB
    __shared__ unsigned int hist[256];
    __shared__ unsigned int sbuf[256];
    __shared__ unsigned int wsum[16];
    __shared__ unsigned int n_active_sh;
    __shared__ unsigned int sel_bin, sel_knew;

    const int row = blockIdx.x;
    const int tid = threadIdx.x;
    const float* srow = buf + row * SS;
    const int* mrow = mask + row * SS;

    if (tid == 0) n_active_sh = 0;
    __syncthreads();

    // Load keys (order-preserving float->uint map), count active tokens.
    unsigned int mycnt = 0;
    for (int i = tid; i < SS; i += 1024) {
        unsigned int u = __float_as_uint(srow[i]);
        keys[i] = (u & 0x80000000u) ? ~u : (u | 0x80000000u);
        if (mrow[i] != 0) mycnt++;
    }
    atomicAdd(&n_active_sh, mycnt);
    __syncthreads();

    const unsigned int n_active = n_active_sh;
    unsigned int k = (n_active + 1u) >> 1;     // ceil(n*0.5), exact for int n
    if (k < 1u) k = 1u;

    // 4-round radix select (8 bits/round, MSB first) for k-th largest key.
    unsigned int prefix = 0, prefmask = 0;
    for (int round = 0; round < 4; ++round) {
        const int shift = 24 - 8 * round;
        if (tid < 256) hist[tid] = 0;
        __syncthreads();
        for (int i = tid; i < SS; i += 1024) {
            unsigned int key = keys[i];
            if ((key & prefmask) == prefix)
                atomicAdd(&hist[(key >> shift) & 0xFFu], 1u);
        }
        __syncthreads();
        // Cooperative suffix sum: sbuf[b] = count with digit >= b
        if (tid < 256) sbuf[tid] = hist[tid];
        __syncthreads();
        for (int off = 1; off < 256; off <<= 1) {
            unsigned int v = 0;
            if (tid < 256 && tid + off < 256) v = sbuf[tid + off];
            __syncthreads();
            if (tid < 256) sbuf[tid] += v;
            __syncthreads();
        }
        if (tid < 256) {
            unsigned int above = (tid < 255) ? sbuf[tid + 1] : 0u;
            if (sbuf[tid] >= k && above < k) {   // exactly one bin matches
                sel_bin = (unsigned int)tid;
                sel_knew = k - above;
            }
        }
        __syncthreads();
        prefix |= sel_bin << shift;
        prefmask |= 0xFFu << shift;
        k = sel_knew;
        __syncthreads();
    }

    const unsigned int thr = prefix;   // exact key of k-th largest
    const unsigned int k_rem = k;      // how many ==thr to keep (lowest index)

    // Stable tie ranking: contiguous 8-element chunk per thread, block scan.
    const int base = tid * 8;
    unsigned int cnt = 0;
#pragma unroll
    for (int j = 0; j < 8; ++j) cnt += (keys[base + j] == thr) ? 1u : 0u;

    const int lane = tid & 63, wv = tid >> 6;
    unsigned int inc = cnt;
#pragma unroll
    for (int off = 1; off < 64; off <<= 1) {
        unsigned int n = (unsigned int)__shfl_up((int)inc, off, 64);
        if (lane >= off) inc += n;
    }
    if (lane == 63) wsum[wv] = inc;
    __syncthreads();
    if (tid == 0) {
        unsigned int acc = 0;
        for (int i = 0; i < 16; ++i) { unsigned int t = wsum[i]; wsum[i] = acc; acc += t; }
    }
    __syncthreads();
    unsigned int r = wsum[wv] + inc - cnt;   // exclusive rank among ==thr

    // Overwrite buf row with int32 keep mask (reference output is bool->int32)
    int* orow = (int*)(buf + row * SS);
#pragma unroll
    for (int j = 0; j < 8; ++j) {
        const int i = base + j;
        const unsigned int key = keys[i];
        bool keep;
        if (key > thr) keep = true;
        else if (key == thr) { keep = (r < k_rem); r++; }
        else keep = false;
        keep = keep && (mrow[i] != 0);
        orow[i] = keep ? 1 : 0;
    }
}

extern "C" void kernel_launch(void* const* d_in, const int* in_sizes, int n_in,
                              void* d_out, int out_size, void* d_ws, size_t ws_size,
                              hipStream_t stream) {
    const float* hs  = (const float*)d_in[0];   // [B,S,D] fp32
    const int* msk   = (const int*)d_in[1];     // [B,S] int32 0/1 (bool)
    const float* w   = (const float*)d_in[2];   // [D]
    const float* bias= (const float*)d_in[3];   // [1]

    // Stage fp32 scores in d_out, then overwrite in-place with int32 mask.
    float* buf = (float*)d_out;                 // B*S floats = 256 KB

    score_kernel<<<(BB * SS) / 4, 256, 0, stream>>>(hs, msk, w, bias, buf);
    select_kernel<<<BB, 1024, 0, stream>>>(msk, buf);
}